// Round 2
// baseline (240.081 us; speedup 1.0000x reference)
//
#include <hip/hip_runtime.h>
#include <hip/hip_bf16.h>

#define EMBED   256
#define HEADS   8
#define LEVELS  3
#define POINTS  4
#define BATCH   2
#define QLEN    21504
#define SLEN    21504
#define MTOT    (BATCH * QLEN)   // 43008

typedef __attribute__((ext_vector_type(8))) short short8;
typedef __attribute__((ext_vector_type(4))) float f32x4;

__device__ __forceinline__ short f2bf(float x) {
    unsigned u = __builtin_bit_cast(unsigned, x);
    u += 0x7fffu + ((u >> 16) & 1u);      // RNE (inputs are finite)
    return (short)(u >> 16);
}
__device__ __forceinline__ float bf_lo(unsigned u) { return __builtin_bit_cast(float, u << 16); }
__device__ __forceinline__ float bf_hi(unsigned u) { return __builtin_bit_cast(float, u & 0xffff0000u); }
__device__ __forceinline__ void async16(const void* g, void* l) {
    __builtin_amdgcn_global_load_lds((const __attribute__((address_space(1))) void*)g,
                                     (__attribute__((address_space(3))) void*)l, 16, 0, 0);
}

// ---------------- weight pack: bf16 weights + compact so|aw (288 rows) ----------------
__global__ __launch_bounds__(256)
void pack_weights_kernel(const float* __restrict__ vW, const float* __restrict__ oW,
                         const float* __restrict__ soW, const float* __restrict__ awW,
                         const float* __restrict__ soB, const float* __restrict__ awB,
                         short* __restrict__ vWb, short* __restrict__ oWb,
                         short* __restrict__ soawWb, float* __restrict__ soawB)
{
    int i = blockIdx.x * 256 + threadIdx.x;
    if (i < 65536) {
        vWb[i] = f2bf(vW[i]);
    } else if (i < 131072) {
        int j = i - 65536;
        oWb[j] = f2bf(oW[j]);
    } else if (i < 204800) {
        int j = i - 131072;            // [288][256]
        int row = j >> 8, k = j & 255;
        float v = (row < 192) ? soW[row * 256 + k] : awW[(row - 192) * 256 + k];
        soawWb[j] = f2bf(v);
    } else if (i < 205088) {
        int row = i - 204800;          // [288]
        soawB[row] = (row < 192) ? soB[row] : awB[row - 192];
    }
}

// ---------------- A-stationary GEMM: A read ONCE, W col-groups cycled via LDS ----
// Block = 512 thr (8 waves) holds 128 rows of A as bf16 MFMA fragments in VGPRs
// (wave w -> rows strip + w*16 + m16; 8 k-frags of 8 bf16). For each column
// group (<=128 cols, <=64 KB W in LDS): stage via global_load_lds with a
// global-side XOR swizzle, barrier, MFMA sweep, store, barrier, next group.
__device__ __forceinline__
void astat_gemm(const short8* __restrict__ afr, const short* __restrict__ Wt,
                const float* __restrict__ bias, int ngroups, int gcols,
                int rowstrip, short* __restrict__ Ws,
                // epilogue: mode 0 = fp32 [row*ldc+col]; 1 = bf16 head-major value
                int mode, int ldc, void* __restrict__ Cout)
{
    const int tid  = threadIdx.x;
    const int lane = tid & 63;
    const int wv   = tid >> 6;
    const int m16  = lane & 15;
    const int ko   = lane >> 4;
    const int nch  = gcols * 32;          // 16B chunks per group
    const int r0   = rowstrip + wv * 16 + ko * 4;

    for (int gidx = 0; gidx < ngroups; ++gidx) {
        const int colbase = gidx * gcols;
        for (int c = tid; c < nch; c += 512) {
            const int colL = c >> 5;
            const int cw   = c & 31;
            const int csw  = (cw & 24) | ((cw ^ colL) & 7);
            async16(Wt + (((size_t)(colbase + colL)) << 8) + csw * 8, Ws + c * 8);
        }
        __syncthreads();
        const short8* Wvp = (const short8*)Ws;
        const int nct = gcols >> 4;
        for (int ct = 0; ct < nct; ++ct) {
            const int colL = ct * 16 + m16;
            f32x4 a = (f32x4)0.f;
            #pragma unroll
            for (int kt = 0; kt < 8; ++kt) {
                const int g = kt * 4 + ko;
                const int s = (g & 24) | ((g ^ colL) & 7);
                a = __builtin_amdgcn_mfma_f32_16x16x32_bf16(afr[kt], Wvp[colL * 32 + s], a, 0, 0, 0);
            }
            const int col = colbase + colL;
            const float bv = bias[col];
            if (mode == 1) {
                // value: bf16 head-major [B,H,S,32]
                const int h = col >> 5, ch = col & 31;
                #pragma unroll
                for (int r = 0; r < 4; ++r) {
                    const int rg = r0 + r;
                    const int b  = (rg >= SLEN) ? 1 : 0;
                    const int sx = rg - b * SLEN;
                    ((short*)Cout)[(((size_t)(b * 8 + h)) * SLEN + sx) * 32 + ch] = f2bf(a[r] + bv);
                }
            } else {
                #pragma unroll
                for (int r = 0; r < 4; ++r)
                    ((float*)Cout)[(size_t)(r0 + r) * ldc + col] = a[r] + bv;
            }
        }
        __syncthreads();
    }
}

// Projections: blockIdx.x==0 -> value proj (A=enc), ==1 -> offsets+weights (A=hs).
__global__ __launch_bounds__(512)
void proj_gemm_kernel(const float* __restrict__ enc, const short* __restrict__ vWb,
                      const float* __restrict__ vB, short* __restrict__ valb,
                      const float* __restrict__ hs, const short* __restrict__ soawWb,
                      const float* __restrict__ soawB, float* __restrict__ offaw)
{
    __shared__ short Ws[128 * 256];   // 64 KB
    const int tid = threadIdx.x;
    const int lane = tid & 63, wv = tid >> 6;
    const int m16 = lane & 15, ko = lane >> 4;
    const int rowstrip = blockIdx.y * 128;
    const bool isVal = (blockIdx.x == 0);
    const float* A = isVal ? enc : hs;
    const int row = rowstrip + wv * 16 + m16;

    short8 afr[8];
    const float* Af = A + (size_t)row * 256 + ko * 8;
    #pragma unroll
    for (int kt = 0; kt < 8; ++kt) {
        float4 x = *(const float4*)(Af + kt * 32);
        float4 y = *(const float4*)(Af + kt * 32 + 4);
        short8 t;
        t[0] = f2bf(x.x); t[1] = f2bf(x.y); t[2] = f2bf(x.z); t[3] = f2bf(x.w);
        t[4] = f2bf(y.x); t[5] = f2bf(y.y); t[6] = f2bf(y.z); t[7] = f2bf(y.w);
        afr[kt] = t;
    }

    if (isVal) astat_gemm(afr, vWb,    vB,    2, 128, rowstrip, Ws, 1, 256, valb);
    else       astat_gemm(afr, soawWb, soawB, 3,  96, rowstrip, Ws, 0, 288, offaw);
}

// Output projection: A = attn bf16 [M,256], read once; out fp32.
__global__ __launch_bounds__(512)
void out_gemm_kernel(const short* __restrict__ A, const short* __restrict__ oWb,
                     const float* __restrict__ oB, float* __restrict__ C)
{
    __shared__ short Ws[128 * 256];   // 64 KB
    const int tid = threadIdx.x;
    const int lane = tid & 63, wv = tid >> 6;
    const int m16 = lane & 15, ko = lane >> 4;
    const int rowstrip = blockIdx.x * 128;
    const int row = rowstrip + wv * 16 + m16;

    short8 afr[8];
    const short* Ab = A + (size_t)row * 256 + ko * 8;
    #pragma unroll
    for (int kt = 0; kt < 8; ++kt) afr[kt] = *(const short8*)(Ab + kt * 32);

    astat_gemm(afr, oWb, oB, 2, 128, rowstrip, Ws, 0, 256, C);
}

// ---------------- Sampling: one (b,h) per block, XCD-affine for L2 residency ----
// value [B,H,S,32] bf16: one (b,h) slice = 21504*64B = 1.34 MB < 4 MB per-XCD L2.
// 10752 blocks; round-robin dispatch puts blockIdx.x % 8 on XCD (blk & 7), so we
// bind h = blk & 7 -> every block resident on an XCD gathers from the SAME
// 1.34 MB value slice -> gathers become L2 hits instead of Infinity-Cache reads.
// b = (blk>>3)/672 (two sequential phases), query chunk = (blk>>3)%672, 32
// queries/block (21504 = 672*32). Group = 8 lanes (texel t = sub>>2, channel
// chunk = sub&3); per point only 2 loads (row y0 pair, row y1 pair), each
// 8x16B = 128 B contiguous. Prep/gather math identical to the verified kernel.
__global__ __launch_bounds__(256)
void msda_sample_kernel(const short* __restrict__ value,  // [B,H,S,32] bf16
                        const float* __restrict__ offaw,  // [M,288]: 0..191 off, 192..287 aw
                        const float* __restrict__ ref,    // [B,Q,L,2] fp32
                        short* __restrict__ attn)         // [M,256] bf16
{
    __shared__ int prep[32 * 76];    // per group: 12 pts x 6 words {i0,i1,w00,w01,w10,w11}

    const int tid = threadIdx.x;
    const int g   = tid >> 3;        // 0..31 : query within block
    const int sub = tid & 7;         // 0..7
    const int t   = sub >> 2;        // texel within pair

    const int blk = blockIdx.x;
    const int h   = blk & 7;         // XCD-affine head
    const int j   = blk >> 3;        // 0..1343
    const int b   = (j >= 672) ? 1 : 0;
    const int qc  = j - b * 672;     // 0..671
    const int q   = qc * 32 + g;
    const int bq  = b * QLEN + q;

    // ---- Phase 1: prep. sub 0..7 -> point sub; sub 0..3 also point sub+8 ----
    {
        // 12 aw floats: 16B-aligned (1152*bq + 768 + 48*h), load as 3 x float4
        const float* awp = offaw + (size_t)bq * 288 + 192 + h * 12;
        const float4 wa = *(const float4*)(awp);
        const float4 wb = *(const float4*)(awp + 4);
        const float4 wc = *(const float4*)(awp + 8);
        float w[12] = { wa.x, wa.y, wa.z, wa.w, wb.x, wb.y, wb.z, wb.w,
                        wc.x, wc.y, wc.z, wc.w };
        float mx = w[0];
        #pragma unroll
        for (int i = 1; i < 12; ++i) mx = fmaxf(mx, w[i]);
        float s = 0.f;
        #pragma unroll
        for (int i = 0; i < 12; ++i) s += __expf(w[i] - mx);
        const float inv = 1.f / s;

        const float* offp = offaw + (size_t)bq * 288 + h * 24;
        const float* refp = ref + (size_t)bq * 6;
        const int npts = (sub < 4) ? 2 : 1;
        #pragma unroll
        for (int it = 0; it < 2; ++it) {
            if (it >= npts) break;
            const int p  = sub + it * 8;      // 0..11
            const int l  = p >> 2;
            const int Wl = 128 >> l;
            const int st = (l == 0) ? 0 : (l == 1 ? 16384 : 20480);

            const float2 oxy = *(const float2*)(offp + p * 2);   // 8B-aligned
            const float2 rxy = *(const float2*)(refp + 2 * l);   // 8B-aligned
            const float ox = oxy.x, oy = oxy.y;
            const float rx = rxy.x, ry = rxy.y;
            const float a  = __expf(w[p] - mx) * inv;

            const float x = fmaf(rx, (float)Wl, ox - 0.5f);
            const float y = fmaf(ry, (float)Wl, oy - 0.5f);
            const float x0f = floorf(x), y0f = floorf(y);
            const int   x0  = (int)x0f,  y0  = (int)y0f;
            const float wx1 = x - x0f, wy1 = y - y0f;
            const float wx0 = 1.f - wx1, wy0 = 1.f - wy1;
            const bool vy0 = (unsigned)y0       < (unsigned)Wl;
            const bool vy1 = (unsigned)(y0 + 1) < (unsigned)Wl;

            const int xs = min(max(x0, 0), Wl - 2);   // pair start, always in-bounds
            // per-texel x-weights (0 when that texel isn't a valid bilinear corner)
            const float wl0 = (xs == x0) ? wx0 : ((xs == x0 + 1) ? wx1 : 0.f);
            const float wl1 = (xs == x0) ? wx1 : ((xs + 1 == x0) ? wx0 : 0.f);

            const int hb = (b * 8 + h) * SLEN + st;   // wave-uniform base
            const int i0 = vy0 ? (hb + y0 * Wl + xs) * 4       : 0;
            const int i1 = vy1 ? (hb + (y0 + 1) * Wl + xs) * 4 : 0;

            int* pp = &prep[g * 76 + p * 6];
            pp[0] = i0;
            pp[1] = i1;
            pp[2] = __builtin_bit_cast(int, vy0 ? wy0 * wl0 * a : 0.f);
            pp[3] = __builtin_bit_cast(int, vy0 ? wy0 * wl1 * a : 0.f);
            pp[4] = __builtin_bit_cast(int, vy1 ? wy1 * wl0 * a : 0.f);
            pp[5] = __builtin_bit_cast(int, vy1 ? wy1 * wl1 * a : 0.f);
        }
    }
    __syncthreads();

    // ---- Phase 2: gather ----
    const int4* vp = (const int4*)value;
    float acc[8];
    #pragma unroll
    for (int j2 = 0; j2 < 8; ++j2) acc[j2] = 0.f;

    #pragma unroll
    for (int p = 0; p < 12; ++p) {
        const int* pp = &prep[g * 76 + p * 6];
        const int i0 = pp[0];
        const int i1 = pp[1];
        const float w0 = __builtin_bit_cast(float, pp[2 + t]);
        const float w1 = __builtin_bit_cast(float, pp[4 + t]);
        const int4 v0 = vp[i0 + sub];
        const int4 v1 = vp[i1 + sub];
        #define ACCUM(V, W) \
            acc[0] = fmaf(W, bf_lo((unsigned)V.x), acc[0]); \
            acc[1] = fmaf(W, bf_hi((unsigned)V.x), acc[1]); \
            acc[2] = fmaf(W, bf_lo((unsigned)V.y), acc[2]); \
            acc[3] = fmaf(W, bf_hi((unsigned)V.y), acc[3]); \
            acc[4] = fmaf(W, bf_lo((unsigned)V.z), acc[4]); \
            acc[5] = fmaf(W, bf_hi((unsigned)V.z), acc[5]); \
            acc[6] = fmaf(W, bf_hi ? bf_lo((unsigned)V.w) : bf_lo((unsigned)V.w), acc[6]); \
            acc[7] = fmaf(W, bf_hi((unsigned)V.w), acc[7]);
        #undef ACCUM
        #define ACCUM(V, W) \
            acc[0] = fmaf(W, bf_lo((unsigned)V.x), acc[0]); \
            acc[1] = fmaf(W, bf_hi((unsigned)V.x), acc[1]); \
            acc[2] = fmaf(W, bf_lo((unsigned)V.y), acc[2]); \
            acc[3] = fmaf(W, bf_hi((unsigned)V.y), acc[3]); \
            acc[4] = fmaf(W, bf_lo((unsigned)V.z), acc[4]); \
            acc[5] = fmaf(W, bf_hi((unsigned)V.z), acc[5]); \
            acc[6] = fmaf(W, bf_lo((unsigned)V.w), acc[6]); \
            acc[7] = fmaf(W, bf_hi((unsigned)V.w), acc[7]);
        ACCUM(v0, w0) ACCUM(v1, w1)
        #undef ACCUM
    }

    // combine the two texel partial sums (lane <-> lane^4, same 8-lane group)
    #pragma unroll
    for (int j2 = 0; j2 < 8; ++j2) acc[j2] += __shfl_xor(acc[j2], 4);

    if (sub < 4) {
        int4 o;
        o.x = ((unsigned)(unsigned short)f2bf(acc[1]) << 16) | (unsigned short)f2bf(acc[0]);
        o.y = ((unsigned)(unsigned short)f2bf(acc[3]) << 16) | (unsigned short)f2bf(acc[2]);
        o.z = ((unsigned)(unsigned short)f2bf(acc[5]) << 16) | (unsigned short)f2bf(acc[4]);
        o.w = ((unsigned)(unsigned short)f2bf(acc[7]) << 16) | (unsigned short)f2bf(acc[6]);
        ((int4*)attn)[(size_t)bq * 32 + h * 4 + sub] = o;
    }
}

// ---------------- launch ----------------
extern "C" void kernel_launch(void* const* d_in, const int* in_sizes, int n_in,
                              void* d_out, int out_size, void* d_ws, size_t ws_size,
                              hipStream_t stream) {
    const float* hs  = (const float*)d_in[0];
    const float* enc = (const float*)d_in[1];
    const float* rp  = (const float*)d_in[2];
    const float* soW = (const float*)d_in[4];
    const float* soB = (const float*)d_in[5];
    const float* awW = (const float*)d_in[6];
    const float* awB = (const float*)d_in[7];
    const float* vW  = (const float*)d_in[8];
    const float* vB  = (const float*)d_in[9];
    const float* oW  = (const float*)d_in[10];
    const float* oB  = (const float*)d_in[11];
    float* out = (float*)d_out;

    const int M = MTOT;                       // 43008
    const size_t ME = (size_t)M * 256;

    short* valb   = (short*)d_ws;             // [B,H,S,32] bf16 head-major
    short* attnb  = valb + ME;                // [M,256] bf16
    float* offaw  = (float*)(attnb + ME);     // [M,288] fp32 compact
    short* vWb    = (short*)(offaw + (size_t)M * 288);
    short* oWb    = vWb + 65536;
    short* soawWb = oWb + 65536;              // [288,256] bf16
    float* soawB  = (float*)(soawWb + 73728); // [288] fp32

    pack_weights_kernel<<<dim3(802), dim3(256), 0, stream>>>(vW, oW, soW, awW, soB, awB,
                                                             vWb, oWb, soawWb, soawB);
    // value + offsets/weights projections (A read once per kernel part)
    proj_gemm_kernel<<<dim3(2, M / 128), dim3(512), 0, stream>>>(enc, vWb, vB, valb,
                                                                 hs, soawWb, soawB, offaw);
    // sampling -> attn bf16 (XCD-affine head binding)
    msda_sample_kernel<<<dim3(M / 4), dim3(256), 0, stream>>>(valb, offaw, rp, attnb);
    // output projection
    out_gemm_kernel<<<dim3(M / 128), dim3(512), 0, stream>>>(attnb, oWb, oB, out);
}